// Round 3
// baseline (756.470 us; speedup 1.0000x reference)
//
#include <hip/hip_runtime.h>
#include <math.h>

// Problem constants
#define BATCH 32
#define H 512
#define W 512
#define OUT_HW 502          // 512 - 11 + 1
#define TS 32               // output tile (x and y)
#define IN_TS 42            // TS + 10
#define RB_STRIDE 36        // row-blur LDS row stride (floats), mult of 4
#define NBX 16
#define NBY 16
#define NBLOCKS (NBX * NBY * BATCH)   // 8192

struct GaussW { float g[11]; };

// R3 design notes:
//  - No sp/st LDS staging: stage 2 reads pred/targ directly from global
//    (block region 14.8 KB fits L1; halo overlap served by L2). Saves
//    14.8 KB LDS and one barrier. LDS = rb only (30.2 KB) -> 5 blocks/CU.
//  - Stage 3 uses 128 threads (2 rows x 4 cols): acc = 40 floats, no spill.
//  - __launch_bounds__(256,4): cap 128 VGPR. R1 lesson: (256,3)=170-cap
//    spilled the 80-float acc; now acc is 40 floats, ~80-100 VGPR needed.
__global__ __launch_bounds__(256, 4)
void ssim_tile_kernel(const float* __restrict__ pred,
                      const float* __restrict__ targ,
                      float* __restrict__ ws_ssim,
                      float* __restrict__ ws_mse,
                      GaussW gw)
{
    __shared__ __align__(16) float rb[5][IN_TS * RB_STRIDE];
    __shared__ float red[8];

    const int tid = threadIdx.x;
    const int tx = blockIdx.x, ty = blockIdx.y, b = blockIdx.z;
    const int ox0 = tx * TS, oy0 = ty * TS;
    const int rows = min(TS, OUT_HW - oy0);   // valid output rows this tile
    const int cols = min(TS, OUT_HW - ox0);   // valid output cols this tile

    const float* __restrict__ pb = pred + (size_t)b * H * W;
    const float* __restrict__ tb = targ + (size_t)b * H * W;

    // ---- MSE over this block's owned 32x32 input region (exact cover of 512x512)
    float mse_local;
    {
        int r = tid >> 3, c = (tid & 7) * 4;          // 32 rows x 8 f4 groups
        const float* prow = pb + (size_t)(oy0 + r) * W + (ox0 + c);
        const float* trow = tb + (size_t)(oy0 + r) * W + (ox0 + c);
        float4 vp = *(const float4*)prow;
        float4 vt = *(const float4*)trow;
        float dx = vp.x - vt.x, dy = vp.y - vt.y, dz = vp.z - vt.z, dw = vp.w - vt.w;
        mse_local = dx * dx + dy * dy + dz * dz + dw * dw;
    }

    // ---- Stage 2: horizontal blur of 5 channels, global -> registers -> rb
    // Input rows needed: oy0 .. oy0+rrows-1, always < H by construction.
    const int rrows = rows + 10;
    for (int idx = tid; idx < rrows * 8; idx += 256) {
        int r = idx >> 3, gq = idx & 7;
        int c0 = 4 * gq;
        const float* prow = pb + (size_t)(oy0 + r) * W;
        const float* trow = tb + (size_t)(oy0 + r) * W;
        float pv[16], tv[16];
        #pragma unroll
        for (int q = 0; q < 4; ++q) {
            int gx = ox0 + c0 + 4 * q;
            float4 vp = make_float4(0.f, 0.f, 0.f, 0.f);
            float4 vt = vp;
            if (gx < W) {                 // gx is 16B-aligned; all-or-nothing
                vp = *(const float4*)(prow + gx);
                vt = *(const float4*)(trow + gx);
            }
            *(float4*)(pv + 4 * q) = vp;
            *(float4*)(tv + 4 * q) = vt;
        }

        float a[5][4] = {};
        #pragma unroll
        for (int k = 0; k < 11; ++k) {
            float g = gw.g[k];
            #pragma unroll
            for (int j = 0; j < 4; ++j) {
                float p = pv[j + k], t = tv[j + k];
                float gp = g * p, gt = g * t;
                a[0][j] += gp;
                a[1][j] += gt;
                a[2][j] = fmaf(gp, p, a[2][j]);
                a[3][j] = fmaf(gt, t, a[3][j]);
                a[4][j] = fmaf(gp, t, a[4][j]);
            }
        }
        #pragma unroll
        for (int ch = 0; ch < 5; ++ch) {
            *(float4*)(&rb[ch][r * RB_STRIDE + c0]) =
                make_float4(a[ch][0], a[ch][1], a[ch][2], a[ch][3]);
        }
    }
    __syncthreads();

    // ---- Stage 3: vertical blur, 128 threads, 2 rows x 4 cols each
    float ssim_local = 0.f;
    if (tid < 128) {
        int rg = tid >> 3, gq = tid & 7;
        int r0 = rg * 2, c0 = 4 * gq;
        if (r0 < rows) {
            float acc[5][2][4] = {};   // [ch][row i][col j]
            #pragma unroll
            for (int jr = 0; jr < 12; ++jr) {
                int rr = r0 + jr;
                #pragma unroll
                for (int ch = 0; ch < 5; ++ch) {
                    float4 v = *(const float4*)(&rb[ch][rr * RB_STRIDE + c0]);
                    #pragma unroll
                    for (int i = 0; i < 2; ++i) {
                        int k = jr - i;
                        if (k >= 0 && k < 11) {
                            float g = gw.g[k];
                            acc[ch][i][0] = fmaf(g, v.x, acc[ch][i][0]);
                            acc[ch][i][1] = fmaf(g, v.y, acc[ch][i][1]);
                            acc[ch][i][2] = fmaf(g, v.z, acc[ch][i][2]);
                            acc[ch][i][3] = fmaf(g, v.w, acc[ch][i][3]);
                        }
                    }
                }
            }
            const float C1 = 1e-4f, C2 = 9e-4f;
            #pragma unroll
            for (int i = 0; i < 2; ++i) {
                if (r0 + i < rows) {
                    #pragma unroll
                    for (int j = 0; j < 4; ++j) {
                        if (c0 + j < cols) {
                            float mu1 = acc[0][i][j], mu2 = acc[1][i][j];
                            float xx = acc[2][i][j], yy = acc[3][i][j], xy = acc[4][i][j];
                            float mu1s = mu1 * mu1, mu2s = mu2 * mu2, mu12 = mu1 * mu2;
                            float s1 = xx - mu1s;
                            float s2 = yy - mu2s;
                            float s12 = xy - mu12;
                            float num = (2.f * mu12 + C1) * (2.f * s12 + C2);
                            float den = (mu1s + mu2s + C1) * (s1 + s2 + C2) + 1e-6f;
                            ssim_local += num / den;
                        }
                    }
                }
            }
        }
    }

    // ---- Block reduction (256 threads = 4 waves)
    #pragma unroll
    for (int off = 32; off > 0; off >>= 1) {
        ssim_local += __shfl_down(ssim_local, off, 64);
        mse_local  += __shfl_down(mse_local,  off, 64);
    }
    int wave = tid >> 6;
    if ((tid & 63) == 0) { red[wave] = ssim_local; red[4 + wave] = mse_local; }
    __syncthreads();
    if (tid == 0) {
        float s = red[0] + red[1] + red[2] + red[3];
        float m = red[4] + red[5] + red[6] + red[7];
        int bid = (b * NBY + ty) * NBX + tx;
        ws_ssim[bid] = s;
        ws_mse[bid]  = m;
    }
}

__global__ __launch_bounds__(1024)
void finalize_kernel(const float* __restrict__ ws_ssim,
                     const float* __restrict__ ws_mse,
                     float* __restrict__ out)
{
    __shared__ double rs[1024], rm[1024];
    int tid = threadIdx.x;
    double s = 0.0, m = 0.0;
    for (int i = tid; i < NBLOCKS; i += 1024) {
        s += (double)ws_ssim[i];
        m += (double)ws_mse[i];
    }
    rs[tid] = s; rm[tid] = m;
    __syncthreads();
    for (int off = 512; off > 0; off >>= 1) {
        if (tid < off) { rs[tid] += rs[tid + off]; rm[tid] += rm[tid + off]; }
        __syncthreads();
    }
    if (tid == 0) {
        double mse_mean  = rm[0] / (double)((size_t)BATCH * H * W);
        double ssim_mean = rs[0] / (double)((size_t)BATCH * OUT_HW * OUT_HW);
        out[0] = (float)(0.6 * mse_mean + 0.4 * (1.0 - ssim_mean));
    }
}

extern "C" void kernel_launch(void* const* d_in, const int* in_sizes, int n_in,
                              void* d_out, int out_size, void* d_ws, size_t ws_size,
                              hipStream_t stream)
{
    const float* pred = (const float*)d_in[0];
    const float* targ = (const float*)d_in[1];
    float* out = (float*)d_out;
    float* ws_ssim = (float*)d_ws;
    float* ws_mse  = ws_ssim + NBLOCKS;

    // Gaussian taps: computed host-side in double, normalized, passed by value.
    GaussW gw;
    double g[11], sum = 0.0;
    for (int i = 0; i < 11; ++i) { double x = i - 5.0; g[i] = exp(-x * x / 4.5); sum += g[i]; }
    for (int i = 0; i < 11; ++i) gw.g[i] = (float)(g[i] / sum);

    ssim_tile_kernel<<<dim3(NBX, NBY, BATCH), 256, 0, stream>>>(pred, targ, ws_ssim, ws_mse, gw);
    finalize_kernel<<<1, 1024, 0, stream>>>(ws_ssim, ws_mse, out);
}

// Round 4
// 260.934 us; speedup vs baseline: 2.8991x; 2.8991x over previous
//
#include <hip/hip_runtime.h>
#include <math.h>

// Problem constants
#define BATCH 32
#define H 512
#define W 512
#define OUT_HW 502          // 512 - 11 + 1
#define TS 32               // output tile (x and y)
#define IN_TS 42            // TS + 10
#define RB_STRIDE 36        // row-blur LDS row stride (floats), mult of 4
#define NBX 16
#define NBY 16
#define NBLOCKS (NBX * NBY * BATCH)   // 8192

struct GaussW { float g[11]; };

// Launch-bounds history (do not re-break this):
//   (256,3) R1: VGPR capped 170 -> 84, acc spilled, 280 MB scratch writes, 520 us
//   (256,2) R2: VGPR 128, 29 MB residual spill, 177 us  <- only sane setting seen
//   (256,4) R3: allocator dove to 64 VGPR, 2 GB scratch traffic, 690 us
// R4 = R3 structure (rb-only LDS, 1 barrier, 128-thread stage 3) + (256,2).
__global__ __launch_bounds__(256, 2)
void ssim_tile_kernel(const float* __restrict__ pred,
                      const float* __restrict__ targ,
                      float* __restrict__ ws_ssim,
                      float* __restrict__ ws_mse,
                      GaussW gw)
{
    __shared__ __align__(16) float rb[5][IN_TS * RB_STRIDE];
    __shared__ float red[8];

    const int tid = threadIdx.x;
    const int tx = blockIdx.x, ty = blockIdx.y, b = blockIdx.z;
    const int ox0 = tx * TS, oy0 = ty * TS;
    const int rows = min(TS, OUT_HW - oy0);   // valid output rows this tile
    const int cols = min(TS, OUT_HW - ox0);   // valid output cols this tile

    const float* __restrict__ pb = pred + (size_t)b * H * W;
    const float* __restrict__ tb = targ + (size_t)b * H * W;

    // ---- MSE over this block's owned 32x32 input region (exact cover of 512x512)
    float mse_local;
    {
        int r = tid >> 3, c = (tid & 7) * 4;          // 32 rows x 8 f4 groups
        const float* prow = pb + (size_t)(oy0 + r) * W + (ox0 + c);
        const float* trow = tb + (size_t)(oy0 + r) * W + (ox0 + c);
        float4 vp = *(const float4*)prow;
        float4 vt = *(const float4*)trow;
        float dx = vp.x - vt.x, dy = vp.y - vt.y, dz = vp.z - vt.z, dw = vp.w - vt.w;
        mse_local = dx * dx + dy * dy + dz * dz + dw * dw;
    }

    // ---- Stage 2: horizontal blur of 5 channels, global -> registers -> rb
    const int rrows = rows + 10;
    for (int idx = tid; idx < rrows * 8; idx += 256) {
        int r = idx >> 3, gq = idx & 7;
        int c0 = 4 * gq;
        const float* prow = pb + (size_t)(oy0 + r) * W;
        const float* trow = tb + (size_t)(oy0 + r) * W;
        float pv[16], tv[16];
        #pragma unroll
        for (int q = 0; q < 4; ++q) {
            int gx = ox0 + c0 + 4 * q;
            float4 vp = make_float4(0.f, 0.f, 0.f, 0.f);
            float4 vt = vp;
            if (gx < W) {                 // gx is 16B-aligned; all-or-nothing
                vp = *(const float4*)(prow + gx);
                vt = *(const float4*)(trow + gx);
            }
            *(float4*)(pv + 4 * q) = vp;
            *(float4*)(tv + 4 * q) = vt;
        }

        float a[5][4] = {};
        #pragma unroll
        for (int k = 0; k < 11; ++k) {
            float g = gw.g[k];
            #pragma unroll
            for (int j = 0; j < 4; ++j) {
                float p = pv[j + k], t = tv[j + k];
                float gp = g * p, gt = g * t;
                a[0][j] += gp;
                a[1][j] += gt;
                a[2][j] = fmaf(gp, p, a[2][j]);
                a[3][j] = fmaf(gt, t, a[3][j]);
                a[4][j] = fmaf(gp, t, a[4][j]);
            }
        }
        #pragma unroll
        for (int ch = 0; ch < 5; ++ch) {
            *(float4*)(&rb[ch][r * RB_STRIDE + c0]) =
                make_float4(a[ch][0], a[ch][1], a[ch][2], a[ch][3]);
        }
    }
    __syncthreads();

    // ---- Stage 3: vertical blur, 128 threads, 2 rows x 4 cols each
    float ssim_local = 0.f;
    if (tid < 128) {
        int rg = tid >> 3, gq = tid & 7;
        int r0 = rg * 2, c0 = 4 * gq;
        if (r0 < rows) {
            float acc[5][2][4] = {};   // [ch][row i][col j]
            #pragma unroll
            for (int jr = 0; jr < 12; ++jr) {
                int rr = r0 + jr;
                #pragma unroll
                for (int ch = 0; ch < 5; ++ch) {
                    float4 v = *(const float4*)(&rb[ch][rr * RB_STRIDE + c0]);
                    #pragma unroll
                    for (int i = 0; i < 2; ++i) {
                        int k = jr - i;
                        if (k >= 0 && k < 11) {
                            float g = gw.g[k];
                            acc[ch][i][0] = fmaf(g, v.x, acc[ch][i][0]);
                            acc[ch][i][1] = fmaf(g, v.y, acc[ch][i][1]);
                            acc[ch][i][2] = fmaf(g, v.z, acc[ch][i][2]);
                            acc[ch][i][3] = fmaf(g, v.w, acc[ch][i][3]);
                        }
                    }
                }
            }
            const float C1 = 1e-4f, C2 = 9e-4f;
            #pragma unroll
            for (int i = 0; i < 2; ++i) {
                if (r0 + i < rows) {
                    #pragma unroll
                    for (int j = 0; j < 4; ++j) {
                        if (c0 + j < cols) {
                            float mu1 = acc[0][i][j], mu2 = acc[1][i][j];
                            float xx = acc[2][i][j], yy = acc[3][i][j], xy = acc[4][i][j];
                            float mu1s = mu1 * mu1, mu2s = mu2 * mu2, mu12 = mu1 * mu2;
                            float s1 = xx - mu1s;
                            float s2 = yy - mu2s;
                            float s12 = xy - mu12;
                            float num = (2.f * mu12 + C1) * (2.f * s12 + C2);
                            float den = (mu1s + mu2s + C1) * (s1 + s2 + C2) + 1e-6f;
                            ssim_local += num / den;
                        }
                    }
                }
            }
        }
    }

    // ---- Block reduction (256 threads = 4 waves)
    #pragma unroll
    for (int off = 32; off > 0; off >>= 1) {
        ssim_local += __shfl_down(ssim_local, off, 64);
        mse_local  += __shfl_down(mse_local,  off, 64);
    }
    int wave = tid >> 6;
    if ((tid & 63) == 0) { red[wave] = ssim_local; red[4 + wave] = mse_local; }
    __syncthreads();
    if (tid == 0) {
        float s = red[0] + red[1] + red[2] + red[3];
        float m = red[4] + red[5] + red[6] + red[7];
        int bid = (b * NBY + ty) * NBX + tx;
        ws_ssim[bid] = s;
        ws_mse[bid]  = m;
    }
}

__global__ __launch_bounds__(1024)
void finalize_kernel(const float* __restrict__ ws_ssim,
                     const float* __restrict__ ws_mse,
                     float* __restrict__ out)
{
    __shared__ double rs[1024], rm[1024];
    int tid = threadIdx.x;
    double s = 0.0, m = 0.0;
    for (int i = tid; i < NBLOCKS; i += 1024) {
        s += (double)ws_ssim[i];
        m += (double)ws_mse[i];
    }
    rs[tid] = s; rm[tid] = m;
    __syncthreads();
    for (int off = 512; off > 0; off >>= 1) {
        if (tid < off) { rs[tid] += rs[tid + off]; rm[tid] += rm[tid + off]; }
        __syncthreads();
    }
    if (tid == 0) {
        double mse_mean  = rm[0] / (double)((size_t)BATCH * H * W);
        double ssim_mean = rs[0] / (double)((size_t)BATCH * OUT_HW * OUT_HW);
        out[0] = (float)(0.6 * mse_mean + 0.4 * (1.0 - ssim_mean));
    }
}

extern "C" void kernel_launch(void* const* d_in, const int* in_sizes, int n_in,
                              void* d_out, int out_size, void* d_ws, size_t ws_size,
                              hipStream_t stream)
{
    const float* pred = (const float*)d_in[0];
    const float* targ = (const float*)d_in[1];
    float* out = (float*)d_out;
    float* ws_ssim = (float*)d_ws;
    float* ws_mse  = ws_ssim + NBLOCKS;

    // Gaussian taps: computed host-side in double, normalized, passed by value.
    GaussW gw;
    double g[11], sum = 0.0;
    for (int i = 0; i < 11; ++i) { double x = i - 5.0; g[i] = exp(-x * x / 4.5); sum += g[i]; }
    for (int i = 0; i < 11; ++i) gw.g[i] = (float)(g[i] / sum);

    ssim_tile_kernel<<<dim3(NBX, NBY, BATCH), 256, 0, stream>>>(pred, targ, ws_ssim, ws_mse, gw);
    finalize_kernel<<<1, 1024, 0, stream>>>(ws_ssim, ws_mse, out);
}